// Round 15
// baseline (2034.352 us; speedup 1.0000x reference)
//
#include <hip/hip_runtime.h>
#include <hip/hip_fp8.h>
#include <cstdint>
#include <cstddef>

typedef __bf16 bf16_t;
typedef unsigned char fp8_t;
typedef __attribute__((ext_vector_type(8))) __bf16 bf16x8;
typedef __attribute__((ext_vector_type(4))) float f32x4;

__device__ __forceinline__ void async_cp16(const void* g, void* l) {
    __builtin_amdgcn_global_load_lds(
        (const __attribute__((address_space(1))) void*)g,
        (__attribute__((address_space(3))) void*)l,
        16, 0, 0);
}

__device__ __forceinline__ fp8_t to_fp8(float x) {
    __hip_fp8_e4m3 t(x);
    return t.__x;
}

__device__ __forceinline__ float fast_tanh(float x) {
    float ax = fabsf(x);
    float e = __expf(-2.f * ax);
    float t = (1.f - e) / (1.f + e);
    return x < 0.f ? -t : t;
}
__device__ __forceinline__ float fast_sig(float x) {
    return 1.f / (1.f + __expf(-x));
}

// ---------------- conversion kernels ----------------
__global__ void k_cvt_transpose8(const float* __restrict__ src, fp8_t* __restrict__ dst,
                                 int K, int N) {
    int idx = blockIdx.x * 256 + threadIdx.x;
    if (idx >= K * N) return;
    int k = idx / N, n = idx - k * N;
    dst[(size_t)n * K + k] = to_fp8(src[idx]);
}

__global__ void k_cvt_flat(const float* __restrict__ src, bf16_t* __restrict__ dst, int n) {
    int idx = blockIdx.x * 256 + threadIdx.x;
    if (idx >= n) return;
    dst[idx] = (bf16_t)src[idx];
}

__global__ void k_build_wrz(const float* __restrict__ Wih, const float* __restrict__ Whh,
                            const float* __restrict__ bih, const float* __restrict__ bhh,
                            bf16_t* __restrict__ wrz, float* __restrict__ brz) {
    int idx = blockIdx.x * 256 + threadIdx.x;
    if (idx >= 2048 * 1280) return;
    int n = idx / 1280, c = idx - n * 1280;
    float v = (c < 256) ? Wih[(size_t)n * 256 + c] : Whh[(size_t)n * 1024 + (c - 256)];
    wrz[idx] = (bf16_t)v;
    if (c == 0) brz[n] = bih[n] + bhh[n];
}

// fused input cast: xt -> xh[:,0:256] (bf16); state h -> h0b (bf16) + hs8 (fp8)
__global__ void k_cvt_inputs(const float* __restrict__ xt, const float* __restrict__ state,
                             bf16_t* __restrict__ xh, bf16_t* __restrict__ h0b,
                             fp8_t* __restrict__ hs8, int B) {
    int idx = blockIdx.x * 256 + threadIdx.x;
    if (idx >= B * 1280) return;
    int b = idx / 1280, c = idx - b * 1280;
    if (c < 256) {
        xh[(size_t)b * 1280 + c] = (bf16_t)xt[(size_t)b * 256 + c];
    } else {
        int j = c - 256;
        float v = state[(size_t)b * 1040 + 16 + j];
        h0b[(size_t)b * 1024 + j] = (bf16_t)v;
        hs8[(size_t)b * 1024 + j] = to_fp8(v);
    }
}

enum { EPI_TANH = 0, EPI_RK4 = 1, EPI_SIG = 2, EPI_BIASBF = 3, EPI_FIN = 4 };

// =====================================================================
// fp8 GEMM (RK4 chain): 256x256 tile, BK=64, 1024 threads (16 waves
// 4M x 4N; wave = 64x64, acc[4][4] -- per-thread resources = round 12's
// proven kernel, so 4 waves/SIMD, the TLP regime that gives ~3.2K
// cyc/window).  3-slot LDS 96 KiB (1 block/CU of 16 waves).  One counted
// vmcnt(2) + one raw barrier per K-iter, depth-2 prefetch.  Rule-21
// staging: LDS dest = tid*16 LINEAR (1 DMA/thread/plane); swizzle on
// GLOBAL source col16 (s4 ^ ((row>>1)&3)); read slots kk0: (kg^2swr)*8,
// kk1: ((4|kg)^2swr)*8, swr=(fr>>1)&3 (value-verified rounds 12/14).
// =====================================================================
template <int EPI, int STAGE>
__global__ __launch_bounds__(1024, 4) void gemm256f8(
    const fp8_t* __restrict__ A, int lda,
    const fp8_t* __restrict__ Bt,
    int N, int K,
    const float* __restrict__ bias,
    fp8_t* __restrict__ o8,           // TANH: T8; RK4 0-2: hs8
    const bf16_t* __restrict__ h0b,   // RK4 0-2: h0 (bf16)
    const float* __restrict__ state,  // RK4 3: f32 ld 1040
    bf16_t* __restrict__ kacc,        // RK4: k-sum (bf16)
    bf16_t* __restrict__ xhb)         // RK4 3: = xh + 256 (ld 1280), bf16 ht
{
    __shared__ __align__(16) fp8_t dsA[3][16384];   // 3 x (256 rows x 64 k)
    __shared__ __align__(16) fp8_t dsB[3][16384];

    const int tid  = threadIdx.x;
    const int lane = tid & 63;
    const int wv   = tid >> 6;        // 0..15

    // XCD-aware bijective swizzle (nwg % 8 == 0 for all grids here)
    const int gx  = gridDim.x;
    int bid = blockIdx.y * gx + blockIdx.x;
    const int nwg = gx * gridDim.y;
    bid = (bid & 7) * (nwg >> 3) + (bid >> 3);
    const int bm = (bid / gx) << 8;   // 256-row tiles
    const int bn = (bid % gx) << 8;   // 256-col tiles

    const int wm = (wv >> 2) << 6;    // 0,64,128,192
    const int wn = (wv & 3) << 6;     // 0,64,128,192

    f32x4 acc[4][4] = {};

    // ---- staging: LINEAR LDS dest (tid*16), swizzled global source ----
    const int srow = tid >> 2;                        // 0..255
    const int s4   = tid & 3;                         // 16B slot
    const int scol = ((s4 ^ ((srow >> 1) & 3)) << 4); // swizzled global col (bytes)
    const fp8_t* gA0 = A  + (size_t)(bm + srow) * lda + scol;
    const fp8_t* gB0 = Bt + (size_t)(bn + srow) * K + scol;
    const int d0 = tid << 4;                          // linear LDS bytes (1 plane = 16KB)

    // 2 DMA instrs/thread per K-tile  ->  gate = vmcnt(2)
#define STG(t) do { const int _sl = (t) % 3; const size_t _o = (size_t)(t) << 6; \
        async_cp16(gA0 + _o, (void*)&dsA[_sl][d0]);                              \
        async_cp16(gB0 + _o, (void*)&dsB[_sl][d0]); } while (0)

    // ---- fragment offsets (bytes within a slot), swizzled read ----
    const int fr  = lane & 15;
    const int kg  = lane >> 4;
    const int mS  = ((fr >> 1) & 3) << 1;             // 2*swr
    const int aRow = (wm + fr) * 64;
    const int bRow = (wn + fr) * 64;
    const int sk0 = ((kg ^ mS) & 7) << 3;             // kk = 0
    const int sk1 = (((4 | kg) ^ mS) & 7) << 3;       // kk = 1

    const int NT = K >> 6;

    STG(0);
    STG(1);

    for (int kt = 0; kt < NT; ++kt) {
        if (kt + 1 < NT) asm volatile("s_waitcnt vmcnt(2)" ::: "memory");
        else             asm volatile("s_waitcnt vmcnt(0)" ::: "memory");
        __builtin_amdgcn_s_barrier();

        if (kt + 2 < NT) STG(kt + 2);

        const fp8_t* as = dsA[kt % 3];
        const fp8_t* bs = dsB[kt % 3];
        long a0[4], a1[4], b0[4], b1[4];
#pragma unroll
        for (int i = 0; i < 4; ++i) {
            a0[i] = *(const long*)(as + aRow + i * 1024 + sk0);
            a1[i] = *(const long*)(as + aRow + i * 1024 + sk1);
        }
#pragma unroll
        for (int j = 0; j < 4; ++j) {
            b0[j] = *(const long*)(bs + bRow + j * 1024 + sk0);
            b1[j] = *(const long*)(bs + bRow + j * 1024 + sk1);
        }

        __builtin_amdgcn_s_setprio(1);
#pragma unroll
        for (int i = 0; i < 4; ++i)
#pragma unroll
            for (int j = 0; j < 4; ++j)
                acc[i][j] = __builtin_amdgcn_mfma_f32_16x16x32_fp8_fp8(
                    a0[i], b0[j], acc[i][j], 0, 0, 0);
#pragma unroll
        for (int i = 0; i < 4; ++i)
#pragma unroll
            for (int j = 0; j < 4; ++j)
                acc[i][j] = __builtin_amdgcn_mfma_f32_16x16x32_fp8_fp8(
                    a1[i], b1[j], acc[i][j], 0, 0, 0);
        __builtin_amdgcn_s_setprio(0);
    }
#undef STG

    // C/D layout: col = lane&15, row = (lane>>4)*4 + reg
    const int orow0 = bm + wm + (kg << 2);
    const int ocol0 = bn + wn + fr;
#pragma unroll
    for (int i = 0; i < 4; ++i) {
#pragma unroll
        for (int j = 0; j < 4; ++j) {
#pragma unroll
            for (int r = 0; r < 4; ++r) {
                const int row = orow0 + i * 16 + r;
                const int col = ocol0 + j * 16;
                const float c = acc[i][j][r];
                if constexpr (EPI == EPI_TANH) {
                    o8[(size_t)row * N + col] = to_fp8(fast_tanh(c + bias[col]));
                } else {  // EPI_RK4
                    const float kk = c + bias[col];
                    const size_t hidx = ((size_t)row << 10) + col;
                    if constexpr (STAGE == 0) {
                        const float h0 = (float)h0b[hidx];
                        kacc[hidx] = (bf16_t)kk;
                        o8[hidx] = to_fp8(h0 + 0.05f * kk);
                    } else if constexpr (STAGE == 1) {
                        const float h0 = (float)h0b[hidx];
                        kacc[hidx] = (bf16_t)((float)kacc[hidx] + 2.f * kk);
                        o8[hidx] = to_fp8(h0 + 0.05f * kk);
                    } else if constexpr (STAGE == 2) {
                        const float h0 = (float)h0b[hidx];
                        kacc[hidx] = (bf16_t)((float)kacc[hidx] + 2.f * kk);
                        o8[hidx] = to_fp8(h0 + 0.1f * kk);
                    } else {
                        const float h0 = state[(size_t)row * 1040 + 16 + col];
                        const float ht = h0 + (0.1f / 6.f) * ((float)kacc[hidx] + kk);
                        xhb[(size_t)row * 1280 + col] = (bf16_t)ht;
                    }
                }
            }
        }
    }
}

// =====================================================================
// bf16 GEMM (GRU): 256x256 tile, BK=32, 1024 threads (16 waves 4Mx4N;
// wave = 64x64, acc[4][4]).  3-slot LDS 96 KiB.  One vmcnt(2) + one
// barrier per K-iter, depth-2 prefetch, slot-XOR swizzle (0 conflicts,
// verified).  FIN reads ht from its A operand (bf16, L2-hot).
// =====================================================================
template <int EPI>
__global__ __launch_bounds__(1024, 4) void gemm256bf(
    const bf16_t* __restrict__ A, int lda,
    const bf16_t* __restrict__ Bt,
    int N, int K,
    const float* __restrict__ bias,
    bf16_t* __restrict__ o16,         // SIG: rz; BIASBF: inb
    const bf16_t* __restrict__ rz,    // FIN
    const bf16_t* __restrict__ inb,   // FIN
    float* __restrict__ outp)         // FIN: f32 out ld 1040
{
    __shared__ __align__(16) bf16_t As[3][8192];   // 3 x (256 rows x 32 k)
    __shared__ __align__(16) bf16_t Bs[3][8192];

    const int tid  = threadIdx.x;
    const int lane = tid & 63;
    const int wv   = tid >> 6;        // 0..15

    const int gx  = gridDim.x;
    int bid = blockIdx.y * gx + blockIdx.x;
    const int nwg = gx * gridDim.y;
    if ((nwg & 7) == 0) bid = (bid & 7) * (nwg >> 3) + (bid >> 3);
    const int bm = (bid / gx) << 8;
    const int bn = (bid % gx) << 8;

    const int wm = (wv >> 2) << 6;
    const int wn = (wv & 3) << 6;

    f32x4 acc[4][4] = {};

    const int srow = tid >> 2;                        // 0..255
    const int s4   = tid & 3;
    const int scw  = (s4 ^ ((srow >> 1) & 3)) << 3;   // swizzled col (elems)
    const bf16_t* gA0 = A  + (size_t)(bm + srow) * lda + scw;
    const bf16_t* gB0 = Bt + (size_t)(bn + srow) * K + scw;
    const int ldsOff = tid << 3;                      // elems (16B/thread)

    // 2 DMA instrs/thread per K-tile  ->  gate = vmcnt(2)
#define STG(t) do { const int _sl = (t) % 3; const size_t _o = (size_t)(t) << 5; \
        async_cp16(gA0 + _o, (void*)&As[_sl][ldsOff]);                           \
        async_cp16(gB0 + _o, (void*)&Bs[_sl][ldsOff]); } while (0)

    const int fr = lane & 15;
    const int kg = lane >> 4;
    const int ra = wm + fr;
    const int rb = wn + fr;
    const int aoff0 = ra * 32 + ((kg ^ ((ra >> 1) & 3)) << 3);
    const int boff0 = rb * 32 + ((kg ^ ((rb >> 1) & 3)) << 3);

    const int NT = K >> 5;

    STG(0);
    STG(1);

    for (int kt = 0; kt < NT; ++kt) {
        if (kt + 1 < NT) asm volatile("s_waitcnt vmcnt(2)" ::: "memory");
        else             asm volatile("s_waitcnt vmcnt(0)" ::: "memory");
        __builtin_amdgcn_s_barrier();

        if (kt + 2 < NT) STG(kt + 2);

        const bf16_t* as = &As[kt % 3][0];
        const bf16_t* bs = &Bs[kt % 3][0];
        bf16x8 af[4], bfr[4];
#pragma unroll
        for (int i = 0; i < 4; ++i) af[i]  = *(const bf16x8*)(as + aoff0 + i * 512);
#pragma unroll
        for (int j = 0; j < 4; ++j) bfr[j] = *(const bf16x8*)(bs + boff0 + j * 512);

        __builtin_amdgcn_s_setprio(1);
#pragma unroll
        for (int i = 0; i < 4; ++i)
#pragma unroll
            for (int j = 0; j < 4; ++j)
                acc[i][j] = __builtin_amdgcn_mfma_f32_16x16x32_bf16(af[i], bfr[j], acc[i][j], 0, 0, 0);
        __builtin_amdgcn_s_setprio(0);
    }
#undef STG

    const int orow0 = bm + wm + (kg << 2);
    const int ocol0 = bn + wn + fr;
#pragma unroll
    for (int i = 0; i < 4; ++i) {
#pragma unroll
        for (int j = 0; j < 4; ++j) {
#pragma unroll
            for (int r = 0; r < 4; ++r) {
                const int row = orow0 + i * 16 + r;
                const int col = ocol0 + j * 16;
                const float c = acc[i][j][r];
                if constexpr (EPI == EPI_SIG) {
                    o16[(size_t)row * N + col] = (bf16_t)fast_sig(c + bias[col]);
                } else if constexpr (EPI == EPI_BIASBF) {
                    o16[(size_t)row * N + col] = (bf16_t)(c + bias[col]);
                } else {  // EPI_FIN
                    const float hn  = c + bias[col];
                    const float r_  = (float)rz[((size_t)row << 11) + col];
                    const float z_  = (float)rz[((size_t)row << 11) + 1024 + col];
                    const float inv = (float)inb[((size_t)row << 10) + col];
                    const float nn  = fast_tanh(inv + r_ * hn);
                    const float htv = (float)A[(size_t)row * lda + col];  // ht (bf16, L2-hot)
                    outp[(size_t)row * 1040 + 16 + col] = (1.f - z_) * nn + z_ * htv;
                }
            }
        }
    }
}

// ---------------- readout: out[:, :16] ----------------
__global__ void k_ly(const float* __restrict__ outh, const float* __restrict__ state,
                     const float* __restrict__ Wly, const float* __restrict__ bly,
                     const int* __restrict__ y_type, float* __restrict__ outp, int B) {
    int t = blockIdx.x * 256 + threadIdx.x;
    if (t >= B * 16) return;
    int o = t & 15, b = t >> 4;
    const float4* hrow = (const float4*)(outh + (size_t)b * 1040 + 16);
    float s = bly[o];
#pragma unroll 4
    for (int k4 = 0; k4 < 256; ++k4) {
        float4 h = hrow[k4];
        int k = k4 << 2;
        s += h.x * Wly[(k + 0) * 16 + o] + h.y * Wly[(k + 1) * 16 + o]
           + h.z * Wly[(k + 2) * 16 + o] + h.w * Wly[(k + 3) * 16 + o];
    }
    outp[(size_t)b * 1040 + o] = (y_type[o] == 0) ? s : state[(size_t)b * 1040 + o];
}

// ---------------- launcher ----------------
extern "C" void kernel_launch(void* const* d_in, const int* in_sizes, int n_in,
                              void* d_out, int out_size, void* d_ws, size_t ws_size,
                              hipStream_t stream) {
    const float* state = (const float*)d_in[0];
    const float* xt    = (const float*)d_in[1];
    const float* W1    = (const float*)d_in[2];
    const float* b1    = (const float*)d_in[3];
    const float* W2    = (const float*)d_in[4];
    const float* b2    = (const float*)d_in[5];
    const float* Wih   = (const float*)d_in[6];
    const float* Whh   = (const float*)d_in[7];
    const float* bih   = (const float*)d_in[8];
    const float* bhh   = (const float*)d_in[9];
    const float* Wly   = (const float*)d_in[10];
    const float* bly   = (const float*)d_in[11];
    const int*   y_type = (const int*)d_in[12];
    float* out = (float*)d_out;

    const int B = in_sizes[0] / 1040;   // 32768

    char* ws = (char*)d_ws;
    fp8_t*  w1t8 = (fp8_t*) (ws);                    // 2048 x 1024 fp8
    fp8_t*  w2t8 = (fp8_t*) (ws + 2097152);          // 1024 x 2048 fp8
    bf16_t* wrz  = (bf16_t*)(ws + 4194304);          // 2048 x 1280 bf16
    bf16_t* win  = (bf16_t*)(ws + 9437184);          // 1024 x 256 bf16
    bf16_t* whn  = (bf16_t*)(ws + 9961472);          // 1024 x 1024 bf16
    float*  brz  = (float*) (ws + 12058624);         // 2048
    bf16_t* xh   = (bf16_t*)(ws + 12066816);         // B x 1280 bf16 [x|ht]
    fp8_t*  hs8  = (fp8_t*) (ws + 95952896);         // B x 1024 fp8 stage-h
    bf16_t* kacc = (bf16_t*)(ws + 129507328);        // B x 1024 bf16 k-sum
    fp8_t*  T8   = (fp8_t*) (ws + 196616192);        // B x 2048 fp8 tanh
    bf16_t* h0b  = (bf16_t*)(ws + 263725056);        // B x 1024 bf16 h0
    // overlays (after RK4 completes):
    bf16_t* rz   = (bf16_t*)(ws + 196616192);        // B x 2048 bf16 (over T8+h0b)
    bf16_t* inb  = (bf16_t*)(ws + 95952896);         // B x 1024 bf16 (over hs8+kacc)

    // weight prep + fused input casts
    k_cvt_transpose8<<<(1024 * 2048) / 256, 256, 0, stream>>>(W1, w1t8, 1024, 2048);
    k_cvt_transpose8<<<(2048 * 1024) / 256, 256, 0, stream>>>(W2, w2t8, 2048, 1024);
    k_build_wrz<<<(2048 * 1280) / 256, 256, 0, stream>>>(Wih, Whh, bih, bhh, wrz, brz);
    k_cvt_flat<<<(1024 * 256) / 256, 256, 0, stream>>>(Wih + 2048 * 256, win, 1024 * 256);
    k_cvt_flat<<<(1024 * 1024) / 256, 256, 0, stream>>>(Whh + 2048 * 1024, whn, 1024 * 1024);
    k_cvt_inputs<<<(B * 1280) / 256, 256, 0, stream>>>(xt, state, xh, h0b, hs8, B);

    const int MB = B / 256;   // 128 m-tiles

    // ---- RK4 (fp8 BK=64, 256x256 16-wave blocks: half the windows again) ----
    gemm256f8<EPI_TANH, 0><<<dim3(8, MB), 1024, 0, stream>>>(hs8, 1024, w1t8, 2048, 1024,
        b1, T8, nullptr, nullptr, nullptr, nullptr);
    gemm256f8<EPI_RK4, 0><<<dim3(4, MB), 1024, 0, stream>>>(T8, 2048, w2t8, 1024, 2048,
        b2, hs8, h0b, nullptr, kacc, nullptr);

    gemm256f8<EPI_TANH, 0><<<dim3(8, MB), 1024, 0, stream>>>(hs8, 1024, w1t8, 2048, 1024,
        b1, T8, nullptr, nullptr, nullptr, nullptr);
    gemm256f8<EPI_RK4, 1><<<dim3(4, MB), 1024, 0, stream>>>(T8, 2048, w2t8, 1024, 2048,
        b2, hs8, h0b, nullptr, kacc, nullptr);

    gemm256f8<EPI_TANH, 0><<<dim3(8, MB), 1024, 0, stream>>>(hs8, 1024, w1t8, 2048, 1024,
        b1, T8, nullptr, nullptr, nullptr, nullptr);
    gemm256f8<EPI_RK4, 2><<<dim3(4, MB), 1024, 0, stream>>>(T8, 2048, w2t8, 1024, 2048,
        b2, hs8, h0b, nullptr, kacc, nullptr);

    gemm256f8<EPI_TANH, 0><<<dim3(8, MB), 1024, 0, stream>>>(hs8, 1024, w1t8, 2048, 1024,
        b1, T8, nullptr, nullptr, nullptr, nullptr);
    gemm256f8<EPI_RK4, 3><<<dim3(4, MB), 1024, 0, stream>>>(T8, 2048, w2t8, 1024, 2048,
        b2, nullptr, nullptr, state, kacc, xh + 256);

    // ---- GRU (bf16 256x256 16-wave blocks) ----
    gemm256bf<EPI_SIG><<<dim3(8, MB), 1024, 0, stream>>>(xh, 1280, wrz, 2048, 1280,
        brz, rz, nullptr, nullptr, nullptr);
    gemm256bf<EPI_BIASBF><<<dim3(4, MB), 1024, 0, stream>>>(xh, 1280, win, 1024, 256,
        bih + 2048, inb, nullptr, nullptr, nullptr);
    gemm256bf<EPI_FIN><<<dim3(4, MB), 1024, 0, stream>>>(xh + 256, 1280, whn, 1024, 1024,
        bhh + 2048, nullptr, rz, inb, out);

    // ---- readout out[:, :16] ----
    k_ly<<<(B * 16) / 256, 256, 0, stream>>>(out, state, Wly, bly, y_type, out, B);
}

// Round 16
// 1846.106 us; speedup vs baseline: 1.1020x; 1.1020x over previous
//
#include <hip/hip_runtime.h>
#include <hip/hip_fp8.h>
#include <cstdint>
#include <cstddef>

typedef __bf16 bf16_t;
typedef unsigned char fp8_t;
typedef __attribute__((ext_vector_type(8))) __bf16 bf16x8;
typedef __attribute__((ext_vector_type(4))) float f32x4;

__device__ __forceinline__ void async_cp16(const void* g, void* l) {
    __builtin_amdgcn_global_load_lds(
        (const __attribute__((address_space(1))) void*)g,
        (__attribute__((address_space(3))) void*)l,
        16, 0, 0);
}

__device__ __forceinline__ fp8_t to_fp8(float x) {
    __hip_fp8_e4m3 t(x);
    return t.__x;
}

__device__ __forceinline__ float fast_tanh(float x) {
    float ax = fabsf(x);
    float e = __expf(-2.f * ax);
    float t = (1.f - e) / (1.f + e);
    return x < 0.f ? -t : t;
}
__device__ __forceinline__ float fast_sig(float x) {
    return 1.f / (1.f + __expf(-x));
}

// ---------------- conversion kernels ----------------
__global__ void k_cvt_transpose8(const float* __restrict__ src, fp8_t* __restrict__ dst,
                                 int K, int N) {
    int idx = blockIdx.x * 256 + threadIdx.x;
    if (idx >= K * N) return;
    int k = idx / N, n = idx - k * N;
    dst[(size_t)n * K + k] = to_fp8(src[idx]);
}

__global__ void k_cvt_flat(const float* __restrict__ src, bf16_t* __restrict__ dst, int n) {
    int idx = blockIdx.x * 256 + threadIdx.x;
    if (idx >= n) return;
    dst[idx] = (bf16_t)src[idx];
}

__global__ void k_build_wrz(const float* __restrict__ Wih, const float* __restrict__ Whh,
                            const float* __restrict__ bih, const float* __restrict__ bhh,
                            bf16_t* __restrict__ wrz, float* __restrict__ brz) {
    int idx = blockIdx.x * 256 + threadIdx.x;
    if (idx >= 2048 * 1280) return;
    int n = idx / 1280, c = idx - n * 1280;
    float v = (c < 256) ? Wih[(size_t)n * 256 + c] : Whh[(size_t)n * 1024 + (c - 256)];
    wrz[idx] = (bf16_t)v;
    if (c == 0) brz[n] = bih[n] + bhh[n];
}

// fused input cast: xt -> xh[:,0:256] (bf16); state h -> h0b (bf16) + hs8 (fp8)
__global__ void k_cvt_inputs(const float* __restrict__ xt, const float* __restrict__ state,
                             bf16_t* __restrict__ xh, bf16_t* __restrict__ h0b,
                             fp8_t* __restrict__ hs8, int B) {
    int idx = blockIdx.x * 256 + threadIdx.x;
    if (idx >= B * 1280) return;
    int b = idx / 1280, c = idx - b * 1280;
    if (c < 256) {
        xh[(size_t)b * 1280 + c] = (bf16_t)xt[(size_t)b * 256 + c];
    } else {
        int j = c - 256;
        float v = state[(size_t)b * 1040 + 16 + j];
        h0b[(size_t)b * 1024 + j] = (bf16_t)v;
        hs8[(size_t)b * 1024 + j] = to_fp8(v);
    }
}

enum { EPI_TANH = 0, EPI_RK4 = 1, EPI_SIG = 2, EPI_BIASBF = 3, EPI_FIN = 4 };

// =====================================================================
// fp8 GEMM (RK4 chain): round-12 proven structure.  C = A(MxK)*Bt(NxK)^T,
// e4m3 in, f32 acc.  128x256 tile, BK=64, 512 threads (8 waves 2Mx4N;
// wave = 64x64, acc[4][4]).  3-slot LDS 72 KiB (-> 2 blocks/CU = 4
// waves/SIMD, the measured-optimal window-cost regime ~3.2K cyc).
// One counted vmcnt(3) + one raw barrier per K-iter, depth-2 prefetch.
// Rule-21 staging: LDS dest = tid*16 LINEAR; swizzle on GLOBAL source
// col16 (s4 ^ ((row>>1)&3)); read slots kk0: (kg^2swr)*8, kk1:
// ((4|kg)^2swr)*8, swr=(fr>>1)&3.
// =====================================================================
template <int EPI, int STAGE>
__global__ __launch_bounds__(512, 4) void gemm128f8(
    const fp8_t* __restrict__ A, int lda,
    const fp8_t* __restrict__ Bt,
    int N, int K,
    const float* __restrict__ bias,
    fp8_t* __restrict__ o8,           // TANH: T8; RK4 0-2: hs8
    const bf16_t* __restrict__ h0b,   // RK4 0-2: h0 (bf16)
    const float* __restrict__ state,  // RK4 3: f32 ld 1040
    bf16_t* __restrict__ kacc,        // RK4: k-sum (bf16)
    bf16_t* __restrict__ xhb)         // RK4 3: = xh + 256 (ld 1280), bf16 ht
{
    __shared__ __align__(16) fp8_t dsA[3][8192];    // 3 x (128 rows x 64 k)
    __shared__ __align__(16) fp8_t dsB[3][16384];   // 3 x (256 rows x 64 k)

    const int tid  = threadIdx.x;
    const int lane = tid & 63;
    const int wv   = tid >> 6;

    // XCD-aware bijective swizzle (nwg % 8 == 0 for all grids here)
    const int gx  = gridDim.x;
    int bid = blockIdx.y * gx + blockIdx.x;
    const int nwg = gx * gridDim.y;
    bid = (bid & 7) * (nwg >> 3) + (bid >> 3);
    const int bm = (bid / gx) << 7;   // 128-row tiles
    const int bn = (bid % gx) << 8;   // 256-col tiles

    const int wm = (wv >> 2) << 6;    // 0 or 64
    const int wn = (wv & 3) << 6;     // 0,64,128,192

    f32x4 acc[4][4] = {};

    // ---- staging: LINEAR LDS dest (tid*16), swizzled global source ----
    const int srow = tid >> 2;                        // 0..127
    const int s4   = tid & 3;                         // 16B slot
    const int scol = ((s4 ^ ((srow >> 1) & 3)) << 4); // swizzled global col (bytes)
    const fp8_t* gA0 = A  + (size_t)(bm + srow) * lda + scol;
    const fp8_t* gB0 = Bt + (size_t)(bn + srow) * K + scol;
    const fp8_t* gB1 = gB0 + (size_t)128 * K;         // rows+128: swizzle invariant
    const int d0 = tid << 4;                          // linear LDS bytes

    // 3 DMA instrs/thread per K-tile  ->  gate = vmcnt(3)
#define STG(t) do { const int _sl = (t) % 3; const size_t _o = (size_t)(t) << 6; \
        async_cp16(gA0 + _o, (void*)&dsA[_sl][d0]);                              \
        async_cp16(gB0 + _o, (void*)&dsB[_sl][d0]);                              \
        async_cp16(gB1 + _o, (void*)&dsB[_sl][8192 + d0]); } while (0)

    // ---- fragment offsets (bytes within a slot), swizzled read ----
    const int fr  = lane & 15;
    const int kg  = lane >> 4;
    const int mS  = ((fr >> 1) & 3) << 1;             // 2*swr
    const int aRow = (wm + fr) * 64;
    const int bRow = (wn + fr) * 64;
    const int sk0 = ((kg ^ mS) & 7) << 3;             // kk = 0
    const int sk1 = (((4 | kg) ^ mS) & 7) << 3;       // kk = 1

    const int NT = K >> 6;

    STG(0);
    STG(1);

    for (int kt = 0; kt < NT; ++kt) {
        if (kt + 1 < NT) asm volatile("s_waitcnt vmcnt(3)" ::: "memory");
        else             asm volatile("s_waitcnt vmcnt(0)" ::: "memory");
        __builtin_amdgcn_s_barrier();

        if (kt + 2 < NT) STG(kt + 2);

        const fp8_t* as = dsA[kt % 3];
        const fp8_t* bs = dsB[kt % 3];
        long a0[4], a1[4], b0[4], b1[4];
#pragma unroll
        for (int i = 0; i < 4; ++i) {
            a0[i] = *(const long*)(as + aRow + i * 1024 + sk0);
            a1[i] = *(const long*)(as + aRow + i * 1024 + sk1);
        }
#pragma unroll
        for (int j = 0; j < 4; ++j) {
            b0[j] = *(const long*)(bs + bRow + j * 1024 + sk0);
            b1[j] = *(const long*)(bs + bRow + j * 1024 + sk1);
        }

        __builtin_amdgcn_s_setprio(1);
#pragma unroll
        for (int i = 0; i < 4; ++i)
#pragma unroll
            for (int j = 0; j < 4; ++j)
                acc[i][j] = __builtin_amdgcn_mfma_f32_16x16x32_fp8_fp8(
                    a0[i], b0[j], acc[i][j], 0, 0, 0);
#pragma unroll
        for (int i = 0; i < 4; ++i)
#pragma unroll
            for (int j = 0; j < 4; ++j)
                acc[i][j] = __builtin_amdgcn_mfma_f32_16x16x32_fp8_fp8(
                    a1[i], b1[j], acc[i][j], 0, 0, 0);
        __builtin_amdgcn_s_setprio(0);
    }
#undef STG

    // C/D layout: col = lane&15, row = (lane>>4)*4 + reg
    const int orow0 = bm + wm + (kg << 2);
    const int ocol0 = bn + wn + fr;
#pragma unroll
    for (int i = 0; i < 4; ++i) {
#pragma unroll
        for (int j = 0; j < 4; ++j) {
#pragma unroll
            for (int r = 0; r < 4; ++r) {
                const int row = orow0 + i * 16 + r;
                const int col = ocol0 + j * 16;
                const float c = acc[i][j][r];
                if constexpr (EPI == EPI_TANH) {
                    o8[(size_t)row * N + col] = to_fp8(fast_tanh(c + bias[col]));
                } else {  // EPI_RK4
                    const float kk = c + bias[col];
                    const size_t hidx = ((size_t)row << 10) + col;
                    if constexpr (STAGE == 0) {
                        const float h0 = (float)h0b[hidx];
                        kacc[hidx] = (bf16_t)kk;
                        o8[hidx] = to_fp8(h0 + 0.05f * kk);
                    } else if constexpr (STAGE == 1) {
                        const float h0 = (float)h0b[hidx];
                        kacc[hidx] = (bf16_t)((float)kacc[hidx] + 2.f * kk);
                        o8[hidx] = to_fp8(h0 + 0.05f * kk);
                    } else if constexpr (STAGE == 2) {
                        const float h0 = (float)h0b[hidx];
                        kacc[hidx] = (bf16_t)((float)kacc[hidx] + 2.f * kk);
                        o8[hidx] = to_fp8(h0 + 0.1f * kk);
                    } else {
                        const float h0 = state[(size_t)row * 1040 + 16 + col];
                        const float ht = h0 + (0.1f / 6.f) * ((float)kacc[hidx] + kk);
                        xhb[(size_t)row * 1280 + col] = (bf16_t)ht;
                    }
                }
            }
        }
    }
}

// =====================================================================
// bf16 GEMM (GRU): round-4/12 proven structure.  128x256 tile, BK=32,
// 512 threads (8 waves 2x4; wave = 64x64, acc[4][4]), 3-slot LDS 72 KiB,
// one vmcnt(3) + one barrier per K-iter, depth-2 prefetch, slot-XOR
// swizzle (0 conflicts verified).  FIN reads ht from its A operand.
// =====================================================================
template <int EPI>
__global__ __launch_bounds__(512, 4) void gemm128bf(
    const bf16_t* __restrict__ A, int lda,
    const bf16_t* __restrict__ Bt,
    int N, int K,
    const float* __restrict__ bias,
    bf16_t* __restrict__ o16,         // SIG: rz; BIASBF: inb
    const bf16_t* __restrict__ rz,    // FIN
    const bf16_t* __restrict__ inb,   // FIN
    float* __restrict__ outp)         // FIN: f32 out ld 1040
{
    __shared__ __align__(16) bf16_t As[3][4096];   // 3 x (128 rows x 32 k)
    __shared__ __align__(16) bf16_t Bs[3][8192];   // 3 x (256 rows x 32 k)

    const int tid  = threadIdx.x;
    const int lane = tid & 63;
    const int wv   = tid >> 6;

    const int gx  = gridDim.x;
    int bid = blockIdx.y * gx + blockIdx.x;
    const int nwg = gx * gridDim.y;
    if ((nwg & 7) == 0) bid = (bid & 7) * (nwg >> 3) + (bid >> 3);
    const int bm = (bid / gx) << 7;
    const int bn = (bid % gx) << 8;

    const int wm = (wv >> 2) << 6;
    const int wn = (wv & 3) << 6;

    f32x4 acc[4][4] = {};

    const int srow = tid >> 2;                        // 0..127
    const int s4   = tid & 3;
    const int scw  = (s4 ^ ((srow >> 1) & 3)) << 3;   // swizzled col (elems)
    const bf16_t* gA0 = A  + (size_t)(bm + srow) * lda + scw;
    const bf16_t* gB0 = Bt + (size_t)(bn + srow) * K + scw;
    const bf16_t* gB1 = gB0 + (size_t)128 * K;
    const int ldsOff = tid << 3;                      // elems (16B/thread)

#define STG(t) do { const int _sl = (t) % 3; const size_t _o = (size_t)(t) << 5; \
        async_cp16(gA0 + _o, (void*)&As[_sl][ldsOff]);                           \
        async_cp16(gB0 + _o, (void*)&Bs[_sl][ldsOff]);                           \
        async_cp16(gB1 + _o, (void*)&Bs[_sl][4096 + ldsOff]); } while (0)

    const int fr = lane & 15;
    const int kg = lane >> 4;
    const int ra = wm + fr;
    const int rb = wn + fr;
    const int aoff0 = ra * 32 + ((kg ^ ((ra >> 1) & 3)) << 3);
    const int boff0 = rb * 32 + ((kg ^ ((rb >> 1) & 3)) << 3);

    const int NT = K >> 5;

    STG(0);
    STG(1);

    for (int kt = 0; kt < NT; ++kt) {
        if (kt + 1 < NT) asm volatile("s_waitcnt vmcnt(3)" ::: "memory");
        else             asm volatile("s_waitcnt vmcnt(0)" ::: "memory");
        __builtin_amdgcn_s_barrier();

        if (kt + 2 < NT) STG(kt + 2);

        const bf16_t* as = &As[kt % 3][0];
        const bf16_t* bs = &Bs[kt % 3][0];
        bf16x8 af[4], bfr[4];
#pragma unroll
        for (int i = 0; i < 4; ++i) af[i]  = *(const bf16x8*)(as + aoff0 + i * 512);
#pragma unroll
        for (int j = 0; j < 4; ++j) bfr[j] = *(const bf16x8*)(bs + boff0 + j * 512);

        __builtin_amdgcn_s_setprio(1);
#pragma unroll
        for (int i = 0; i < 4; ++i)
#pragma unroll
            for (int j = 0; j < 4; ++j)
                acc[i][j] = __builtin_amdgcn_mfma_f32_16x16x32_bf16(af[i], bfr[j], acc[i][j], 0, 0, 0);
        __builtin_amdgcn_s_setprio(0);
    }
#undef STG

    const int orow0 = bm + wm + (kg << 2);
    const int ocol0 = bn + wn + fr;
#pragma unroll
    for (int i = 0; i < 4; ++i) {
#pragma unroll
        for (int j = 0; j < 4; ++j) {
#pragma unroll
            for (int r = 0; r < 4; ++r) {
                const int row = orow0 + i * 16 + r;
                const int col = ocol0 + j * 16;
                const float c = acc[i][j][r];
                if constexpr (EPI == EPI_SIG) {
                    o16[(size_t)row * N + col] = (bf16_t)fast_sig(c + bias[col]);
                } else if constexpr (EPI == EPI_BIASBF) {
                    o16[(size_t)row * N + col] = (bf16_t)(c + bias[col]);
                } else {  // EPI_FIN
                    const float hn  = c + bias[col];
                    const float r_  = (float)rz[((size_t)row << 11) + col];
                    const float z_  = (float)rz[((size_t)row << 11) + 1024 + col];
                    const float inv = (float)inb[((size_t)row << 10) + col];
                    const float nn  = fast_tanh(inv + r_ * hn);
                    const float htv = (float)A[(size_t)row * lda + col];  // ht (bf16, L2-hot)
                    outp[(size_t)row * 1040 + 16 + col] = (1.f - z_) * nn + z_ * htv;
                }
            }
        }
    }
}

// ---------------- readout: out[:, :16] ----------------
__global__ void k_ly(const float* __restrict__ outh, const float* __restrict__ state,
                     const float* __restrict__ Wly, const float* __restrict__ bly,
                     const int* __restrict__ y_type, float* __restrict__ outp, int B) {
    int t = blockIdx.x * 256 + threadIdx.x;
    if (t >= B * 16) return;
    int o = t & 15, b = t >> 4;
    const float4* hrow = (const float4*)(outh + (size_t)b * 1040 + 16);
    float s = bly[o];
#pragma unroll 4
    for (int k4 = 0; k4 < 256; ++k4) {
        float4 h = hrow[k4];
        int k = k4 << 2;
        s += h.x * Wly[(k + 0) * 16 + o] + h.y * Wly[(k + 1) * 16 + o]
           + h.z * Wly[(k + 2) * 16 + o] + h.w * Wly[(k + 3) * 16 + o];
    }
    outp[(size_t)b * 1040 + o] = (y_type[o] == 0) ? s : state[(size_t)b * 1040 + o];
}

// ---------------- launcher ----------------
extern "C" void kernel_launch(void* const* d_in, const int* in_sizes, int n_in,
                              void* d_out, int out_size, void* d_ws, size_t ws_size,
                              hipStream_t stream) {
    const float* state = (const float*)d_in[0];
    const float* xt    = (const float*)d_in[1];
    const float* W1    = (const float*)d_in[2];
    const float* b1    = (const float*)d_in[3];
    const float* W2    = (const float*)d_in[4];
    const float* b2    = (const float*)d_in[5];
    const float* Wih   = (const float*)d_in[6];
    const float* Whh   = (const float*)d_in[7];
    const float* bih   = (const float*)d_in[8];
    const float* bhh   = (const float*)d_in[9];
    const float* Wly   = (const float*)d_in[10];
    const float* bly   = (const float*)d_in[11];
    const int*   y_type = (const int*)d_in[12];
    float* out = (float*)d_out;

    const int B = in_sizes[0] / 1040;   // 32768

    char* ws = (char*)d_ws;
    fp8_t*  w1t8 = (fp8_t*) (ws);                    // 2048 x 1024 fp8
    fp8_t*  w2t8 = (fp8_t*) (ws + 2097152);          // 1024 x 2048 fp8
    bf16_t* wrz  = (bf16_t*)(ws + 4194304);          // 2048 x 1280 bf16
    bf16_t* win  = (bf16_t*)(ws + 9437184);          // 1024 x 256 bf16
    bf16_t* whn  = (bf16_t*)(ws + 9961472);          // 1024 x 1024 bf16
    float*  brz  = (float*) (ws + 12058624);         // 2048
    bf16_t* xh   = (bf16_t*)(ws + 12066816);         // B x 1280 bf16 [x|ht]
    fp8_t*  hs8  = (fp8_t*) (ws + 95952896);         // B x 1024 fp8 stage-h
    bf16_t* kacc = (bf16_t*)(ws + 129507328);        // B x 1024 bf16 k-sum
    fp8_t*  T8   = (fp8_t*) (ws + 196616192);        // B x 2048 fp8 tanh
    bf16_t* h0b  = (bf16_t*)(ws + 263725056);        // B x 1024 bf16 h0
    // overlays (after RK4 completes):
    bf16_t* rz   = (bf16_t*)(ws + 196616192);        // B x 2048 bf16 (over T8+h0b)
    bf16_t* inb  = (bf16_t*)(ws + 95952896);         // B x 1024 bf16 (over hs8+kacc)

    // weight prep + fused input casts
    k_cvt_transpose8<<<(1024 * 2048) / 256, 256, 0, stream>>>(W1, w1t8, 1024, 2048);
    k_cvt_transpose8<<<(2048 * 1024) / 256, 256, 0, stream>>>(W2, w2t8, 2048, 1024);
    k_build_wrz<<<(2048 * 1280) / 256, 256, 0, stream>>>(Wih, Whh, bih, bhh, wrz, brz);
    k_cvt_flat<<<(1024 * 256) / 256, 256, 0, stream>>>(Wih + 2048 * 256, win, 1024 * 256);
    k_cvt_flat<<<(1024 * 1024) / 256, 256, 0, stream>>>(Whh + 2048 * 1024, whn, 1024 * 1024);
    k_cvt_inputs<<<(B * 1280) / 256, 256, 0, stream>>>(xt, state, xh, h0b, hs8, B);

    const int MB = B / 128;   // 256 m-tiles

    // ---- RK4 (fp8 BK=64 GEMMs: half the barrier windows) ----
    gemm128f8<EPI_TANH, 0><<<dim3(8, MB), 512, 0, stream>>>(hs8, 1024, w1t8, 2048, 1024,
        b1, T8, nullptr, nullptr, nullptr, nullptr);
    gemm128f8<EPI_RK4, 0><<<dim3(4, MB), 512, 0, stream>>>(T8, 2048, w2t8, 1024, 2048,
        b2, hs8, h0b, nullptr, kacc, nullptr);

    gemm128f8<EPI_TANH, 0><<<dim3(8, MB), 512, 0, stream>>>(hs8, 1024, w1t8, 2048, 1024,
        b1, T8, nullptr, nullptr, nullptr, nullptr);
    gemm128f8<EPI_RK4, 1><<<dim3(4, MB), 512, 0, stream>>>(T8, 2048, w2t8, 1024, 2048,
        b2, hs8, h0b, nullptr, kacc, nullptr);

    gemm128f8<EPI_TANH, 0><<<dim3(8, MB), 512, 0, stream>>>(hs8, 1024, w1t8, 2048, 1024,
        b1, T8, nullptr, nullptr, nullptr, nullptr);
    gemm128f8<EPI_RK4, 2><<<dim3(4, MB), 512, 0, stream>>>(T8, 2048, w2t8, 1024, 2048,
        b2, hs8, h0b, nullptr, kacc, nullptr);

    gemm128f8<EPI_TANH, 0><<<dim3(8, MB), 512, 0, stream>>>(hs8, 1024, w1t8, 2048, 1024,
        b1, T8, nullptr, nullptr, nullptr, nullptr);
    gemm128f8<EPI_RK4, 3><<<dim3(4, MB), 512, 0, stream>>>(T8, 2048, w2t8, 1024, 2048,
        b2, nullptr, nullptr, state, kacc, xh + 256);

    // ---- GRU (bf16 round-4 GEMMs) ----
    gemm128bf<EPI_SIG><<<dim3(8, MB), 512, 0, stream>>>(xh, 1280, wrz, 2048, 1280,
        brz, rz, nullptr, nullptr, nullptr);
    gemm128bf<EPI_BIASBF><<<dim3(4, MB), 512, 0, stream>>>(xh, 1280, win, 1024, 256,
        bih + 2048, inb, nullptr, nullptr, nullptr);
    gemm128bf<EPI_FIN><<<dim3(4, MB), 512, 0, stream>>>(xh + 256, 1280, whn, 1024, 1024,
        bhh + 2048, nullptr, rz, inb, out);

    // ---- readout out[:, :16] ----
    k_ly<<<(B * 16) / 256, 256, 0, stream>>>(out, state, Wly, bly, y_type, out, B);
}